// Round 4
// baseline (125.126 us; speedup 1.0000x reference)
//
#include <hip/hip_runtime.h>
#include <math.h>

// Problem constants (fixed by the reference)
#define BG     64      // b*g = 2*32 groups
#define NN     2048    // nodes per group
#define F      128     // IN_F == 2*OUT_F == 128
#define OUTF   64      // OUT_F
#define NSLICE 16      // node slices per group (128 nodes each)
#define SNODES 128     // nodes per slice

// Workspace layout (float offsets)
#define OFF_WEFF 0                                  // [4][128]
#define OFF_FP   512                                // [BG*NSLICE][4][128] partial pools
#define OFF_LP   (512 + BG * NSLICE * 4 * F)        // [BG*NSLICE][4] partial exp-sums

// ---------------------------------------------------------------------------
// DPP row-sum: 4 rotate-add rounds within each 16-lane row -> every lane
// holds the row total. Pure VALU (no DS pipe, no LDS) — this is what makes
// the register-resident k_main viable (__shfl_xor would emit ds_swizzle:
// ~20 DS ops/node would swamp the LDS pipe).
// ---------------------------------------------------------------------------
template <int CTRL>
__device__ __forceinline__ float dpp_add(float x) {
  int y = __builtin_amdgcn_update_dpp(0, __float_as_int(x), CTRL, 0xF, 0xF, true);
  return x + __int_as_float(y);
}
__device__ __forceinline__ float rowsum16(float x) {
  x = dpp_add<0x121>(x);  // row_ror:1
  x = dpp_add<0x122>(x);  // row_ror:2
  x = dpp_add<0x124>(x);  // row_ror:4
  x = dpp_add<0x128>(x);  // row_ror:8
  return x;
}
__device__ __forceinline__ float dot8(float4 a0, float4 a1, float4 b0, float4 b1) {
  return a0.x * b0.x + a0.y * b0.y + a0.z * b0.z + a0.w * b0.w +
         a1.x * b1.x + a1.y * b1.y + a1.z * b1.z + a1.w * b1.w;
}

// ---------------------------------------------------------------------------
// K1: w_eff[h] = W_h @ a_h. One block per head, fully coalesced float4 W
// reads. score_n = (feat_n @ W) . a = feat_n . (W @ a).
// ---------------------------------------------------------------------------
__global__ __launch_bounds__(256) void k_weff(
    const float* __restrict__ W1, const float* __restrict__ a1,
    const float* __restrict__ W2, const float* __restrict__ a2,
    const float* __restrict__ W3, const float* __restrict__ a3,
    const float* __restrict__ W4, const float* __restrict__ a4,
    float* __restrict__ ws) {
  int h = blockIdx.x, t = threadIdx.x;
  const float* W = (h == 0) ? W1 : (h == 1) ? W2 : (h == 2) ? W3 : W4;
  const float* a = (h == 0) ? a1 : (h == 1) ? a2 : (h == 2) ? a3 : a4;
  __shared__ float aL[F];
  __shared__ float part[F][33];   // +1 pad: conflict-free row sums

  if (t < F) aL[t] = a[t];
  __syncthreads();

  int c = t & 31, r8 = t >> 5;    // chunk, row-octet
#pragma unroll
  for (int it = 0; it < 16; ++it) {
    int row = it * 8 + r8;
    float4 w = ((const float4*)(W + row * F))[c];
    part[row][c] = w.x * aL[4 * c] + w.y * aL[4 * c + 1] +
                   w.z * aL[4 * c + 2] + w.w * aL[4 * c + 3];
  }
  __syncthreads();

  if (t < F) {
    float s = 0.f;
#pragma unroll
    for (int c2 = 0; c2 < 32; ++c2) s += part[t][c2];
    ws[OFF_WEFF + h * F + t] = s;
  }
}

// ---------------------------------------------------------------------------
// K2 (register-resident rewrite): thread (r, c8) owns floats [8*c8..8*c8+7]
// of node-row r. Per node: global->reg load, in-register partial dot for 4
// heads, DPP row_ror reduction (all 16 lanes get the score), exp, and
// e*f accumulation into register accumulators. Features NEVER touch LDS
// (old scheme: 1 LDS write + 2 LDS re-reads per float4 -> ~2100 DS
// cy/block; was LDS/VALU throughput-bound at ~38 us for a 11 us DRAM
// floor). One LDS use remains: the final 16-row combine (34 KB padded,
// 2-way conflict-free, one barrier pair).
// R1 lesson kept: NO __threadfence fusion (agent-scope L2 writeback).
// ---------------------------------------------------------------------------
__global__ __launch_bounds__(256) void k_main(
    const float* __restrict__ feat, float* __restrict__ ws) {
  int g = blockIdx.x >> 4;
  int slice = blockIdx.x & (NSLICE - 1);
  int t = threadIdx.x;
  int r = t >> 4;        // node-row 0..15 (= one DPP row of 16 lanes)
  int c8 = t & 15;       // chunk-of-8 within the feature vector

  // w_eff fragments to registers (L2-resident, one-time per block)
  const float4* wp = (const float4*)(ws + OFF_WEFF);
  float4 w4[4][2];
#pragma unroll
  for (int h = 0; h < 4; ++h) {
    w4[h][0] = wp[h * 32 + c8 * 2 + 0];
    w4[h][1] = wp[h * 32 + c8 * 2 + 1];
  }

  const float4* fb =
      (const float4*)(feat + ((size_t)g * NN + slice * SNODES) * F);

  float4 acc[4][2];      // [head][j]: pooled partials for this thread's 8 floats
#pragma unroll
  for (int h = 0; h < 4; ++h) {
    acc[h][0] = make_float4(0.f, 0.f, 0.f, 0.f);
    acc[h][1] = make_float4(0.f, 0.f, 0.f, 0.f);
  }
  float4 se = make_float4(0.f, 0.f, 0.f, 0.f);  // per-head exp-sums (row-dup)

  // 8 nodes/thread in 2 batches of 4 (keeps ~8 f4 loads in flight, VGPR sane)
#pragma unroll
  for (int kk = 0; kk < 2; ++kk) {
    float4 ld[4][2];
#pragma unroll
    for (int b = 0; b < 4; ++b) {
      int nl = (kk * 4 + b) * 16 + r;
      ld[b][0] = fb[nl * 32 + c8 * 2 + 0];
      ld[b][1] = fb[nl * 32 + c8 * 2 + 1];
    }
#pragma unroll
    for (int b = 0; b < 4; ++b) {
      float px = dot8(ld[b][0], ld[b][1], w4[0][0], w4[0][1]);
      float py = dot8(ld[b][0], ld[b][1], w4[1][0], w4[1][1]);
      float pz = dot8(ld[b][0], ld[b][1], w4[2][0], w4[2][1]);
      float pw = dot8(ld[b][0], ld[b][1], w4[3][0], w4[3][1]);
      px = rowsum16(px); py = rowsum16(py);
      pz = rowsum16(pz); pw = rowsum16(pw);
      // No max-subtraction: Xavier-bounded scores keep exp() in fp32 range.
      float4 e = make_float4(__expf(px), __expf(py), __expf(pz), __expf(pw));
      se.x += e.x; se.y += e.y; se.z += e.z; se.w += e.w;
#pragma unroll
      for (int h = 0; h < 4; ++h) {
        float eh = (h == 0) ? e.x : (h == 1) ? e.y : (h == 2) ? e.z : e.w;
        acc[h][0].x += eh * ld[b][0].x; acc[h][0].y += eh * ld[b][0].y;
        acc[h][0].z += eh * ld[b][0].z; acc[h][0].w += eh * ld[b][0].w;
        acc[h][1].x += eh * ld[b][1].x; acc[h][1].y += eh * ld[b][1].y;
        acc[h][1].z += eh * ld[b][1].z; acc[h][1].w += eh * ld[b][1].w;
      }
    }
  }

  // ---- Final 16-row combine via LDS (once per block) ----
  // red[h][r][33]: 33-f4 row pitch makes write banks (4r+8c8+4j)%32 -> 2-way.
  __shared__ float4 red[4][16][33];
  __shared__ float4 seR[16];
#pragma unroll
  for (int h = 0; h < 4; ++h) {
    red[h][r][c8 * 2 + 0] = acc[h][0];
    red[h][r][c8 * 2 + 1] = acc[h][1];
  }
  if (c8 == 0) seR[r] = se;   // identical across the 16 lanes of a row
  __syncthreads();

  if (t < 128) {
    int h = t >> 5, c4 = t & 31;
    float4 s = make_float4(0.f, 0.f, 0.f, 0.f);
#pragma unroll
    for (int rr = 0; rr < 16; ++rr) {
      float4 v = red[h][rr][c4];
      s.x += v.x; s.y += v.y; s.z += v.z; s.w += v.w;
    }
    ((float4*)(ws + OFF_FP))[(size_t)(g * NSLICE + slice) * 128 + h * 32 + c4] = s;
  }
  if (t == 0) {
    float4 L = make_float4(0.f, 0.f, 0.f, 0.f);
#pragma unroll
    for (int rr = 0; rr < 16; ++rr) {
      float4 v = seR[rr];
      L.x += v.x; L.y += v.y; L.z += v.z; L.w += v.w;
    }
    ((float4*)(ws + OFF_LP))[g * NSLICE + slice] = L;
  }
}

// ---------------------------------------------------------------------------
// K3: combine slice partials, normalize, pooled@W_h, concat@Wo, ELU.
// One block (256 threads) per group; coalesced float4 rows + LDS combine.
// ---------------------------------------------------------------------------
__global__ __launch_bounds__(256) void k_final(
    const float* __restrict__ W1, const float* __restrict__ W2,
    const float* __restrict__ W3, const float* __restrict__ W4,
    const float* __restrict__ Wo, const float* __restrict__ ws,
    float* __restrict__ out) {
  int g = blockIdx.x;
  int t = threadIdx.x;  // 0..255

  // Scratch layout (float4 indices):
  //   f4[0..255]   : pooled half-sums (2 x 128)  -> later Wo GEMV partials
  //   f4[256..383] : normalized fp (4 heads x 128 floats)
  //   f4[512..767] : W-GEMV partials (8 x 32)
  //   f4[768..895] : multi (512 floats)
  __shared__ float4 f4[896];
  __shared__ float invl[4];
  float* fbuf = (float*)f4;

  const float4* FP4 = (const float4*)(ws + OFF_FP) + (size_t)g * NSLICE * 128;

  if (t < 4) {
    float s = 0.f;
#pragma unroll
    for (int sl = 0; sl < NSLICE; ++sl)
      s += ws[OFF_LP + (g * NSLICE + sl) * 4 + t];
    invl[t] = 1.0f / s;
  }
  // Pooled half-sums: thread (j, half) sums 8 slices of element j.
  {
    int j = t & 127, half = t >> 7;
    float4 s4 = make_float4(0.f, 0.f, 0.f, 0.f);
#pragma unroll
    for (int sl = 0; sl < 8; ++sl) {
      float4 v = FP4[(size_t)(half * 8 + sl) * 128 + j];
      s4.x += v.x; s4.y += v.y; s4.z += v.z; s4.w += v.w;
    }
    f4[half * 128 + j] = s4;
  }
  __syncthreads();
  if (t < 128) {
    float4 a = f4[t], b = f4[128 + t];
    float inv = invl[t >> 5];
    f4[256 + t] = make_float4((a.x + b.x) * inv, (a.y + b.y) * inv,
                              (a.z + b.z) * inv, (a.w + b.w) * inv);
  }
  __syncthreads();

  // multi[h*128+col] = fp_h . W_h[:,col] — coalesced float4 rows of W_h,
  // 2 row-groups of 64 per head, LDS partial combine.
  {
    int c = t & 31, rg = (t >> 5) & 1, h = t >> 6;
    const float* Wsel = (h == 0) ? W1 : (h == 1) ? W2 : (h == 2) ? W3 : W4;
    const float4* W4p = (const float4*)Wsel;
    const float* fph = fbuf + 1024 + h * F;  // = f4[256 + h*32 ...]
    float4 acc = make_float4(0.f, 0.f, 0.f, 0.f);
#pragma unroll 8
    for (int k = 0; k < 64; ++k) {
      int i = rg * 64 + k;
      float s = fph[i];
      float4 w = W4p[i * 32 + c];
      acc.x += s * w.x; acc.y += s * w.y; acc.z += s * w.z; acc.w += s * w.w;
    }
    f4[512 + (h * 2 + rg) * 32 + c] = acc;
  }
  __syncthreads();
  if (t < 128) {
    int h = t >> 5, c = t & 31;
    float4 a = f4[512 + (h * 2) * 32 + c];
    float4 b = f4[512 + (h * 2 + 1) * 32 + c];
    f4[768 + h * 32 + c] = make_float4(a.x + b.x, a.y + b.y,
                                       a.z + b.z, a.w + b.w);
  }
  __syncthreads();

  // out[o] = elu(multi . Wo[:,o]) — coalesced float4 rows of Wo,
  // 16 row-groups of 32, LDS partial combine (reuses f4[0..255]).
  {
    int o4 = t & 15, rg = t >> 4;
    const float4* Wo4 = (const float4*)Wo;
    const float* mu = fbuf + 3072;  // = f4[768..]
    float4 acc = make_float4(0.f, 0.f, 0.f, 0.f);
#pragma unroll 8
    for (int k = 0; k < 32; ++k) {
      int i = rg * 32 + k;
      float s = mu[i];
      float4 w = Wo4[i * 16 + o4];
      acc.x += s * w.x; acc.y += s * w.y; acc.z += s * w.z; acc.w += s * w.w;
    }
    f4[rg * 16 + o4] = acc;
  }
  __syncthreads();
  if (t < OUTF) {
    float s = 0.f;
#pragma unroll
    for (int rg = 0; rg < 16; ++rg) s += fbuf[rg * 64 + t];
    out[g * OUTF + t] = (s > 0.f) ? s : expm1f(s);
  }
}

// ---------------------------------------------------------------------------
extern "C" void kernel_launch(void* const* d_in, const int* in_sizes, int n_in,
                              void* d_out, int out_size, void* d_ws, size_t ws_size,
                              hipStream_t stream) {
  const float* feat = (const float*)d_in[0];
  const float* W1 = (const float*)d_in[1];
  const float* a1 = (const float*)d_in[2];
  const float* W2 = (const float*)d_in[3];
  const float* a2 = (const float*)d_in[4];
  const float* W3 = (const float*)d_in[5];
  const float* a3 = (const float*)d_in[6];
  const float* W4 = (const float*)d_in[7];
  const float* a4 = (const float*)d_in[8];
  const float* Wo = (const float*)d_in[9];
  float* ws = (float*)d_ws;
  float* out = (float*)d_out;

  k_weff<<<4, 256, 0, stream>>>(W1, a1, W2, a2, W3, a3, W4, a4, ws);
  k_main<<<BG * NSLICE, 256, 0, stream>>>(feat, ws);
  k_final<<<BG, 256, 0, stream>>>(W1, W2, W3, W4, Wo, ws, out);
}

// Round 5
// 118.052 us; speedup vs baseline: 1.0599x; 1.0599x over previous
//
#include <hip/hip_runtime.h>
#include <math.h>

// Problem constants (fixed by the reference)
#define BG     64      // b*g = 2*32 groups
#define NN     2048    // nodes per group
#define F      128     // IN_F == 2*OUT_F == 128
#define OUTF   64      // OUT_F
#define NSLICE 64      // node slices per group (32 nodes each)
#define SNODES 32      // nodes per slice

// Workspace layout (float offsets)
#define OFF_WEFF 0                                  // [4][128]
#define OFF_FP   512                                // [BG*NSLICE][4][128] partial pools
#define OFF_LP   (512 + BG * NSLICE * 4 * F)        // [BG*NSLICE][4] partial exp-sums

// ---------------------------------------------------------------------------
// DPP row-sum (HW-verified in R4: harness passed with this reduction):
// 4 rotate-add rounds within each 16-lane row -> every lane holds the row
// total. Pure VALU. The 32-lane total is completed with ONE ds_swizzle
// (xor 16) + add — 1 cheap b32 DS op per score instead of staging whole
// feature tiles through LDS.
// ---------------------------------------------------------------------------
template <int CTRL>
__device__ __forceinline__ float dpp_add(float x) {
  int y = __builtin_amdgcn_update_dpp(0, __float_as_int(x), CTRL, 0xF, 0xF, true);
  return x + __int_as_float(y);
}
__device__ __forceinline__ float rowsum16(float x) {
  x = dpp_add<0x121>(x);  // row_ror:1
  x = dpp_add<0x122>(x);  // row_ror:2
  x = dpp_add<0x124>(x);  // row_ror:4
  x = dpp_add<0x128>(x);  // row_ror:8
  return x;
}
__device__ __forceinline__ float sum32(float x) {
  x = rowsum16(x);
  // exchange the two 16-lane row totals within each 32-lane half
  float y = __int_as_float(
      __builtin_amdgcn_ds_swizzle(__float_as_int(x), 0x401F));  // xor lane^16
  return x + y;
}
__device__ __forceinline__ float dot4(float4 a, float4 b) {
  return a.x * b.x + a.y * b.y + a.z * b.z + a.w * b.w;
}

// ---------------------------------------------------------------------------
// K1: w_eff[h] = W_h @ a_h. One block per head, fully coalesced float4 W
// reads. score_n = (feat_n @ W) . a = feat_n . (W @ a).
// ---------------------------------------------------------------------------
__global__ __launch_bounds__(256) void k_weff(
    const float* __restrict__ W1, const float* __restrict__ a1,
    const float* __restrict__ W2, const float* __restrict__ a2,
    const float* __restrict__ W3, const float* __restrict__ a3,
    const float* __restrict__ W4, const float* __restrict__ a4,
    float* __restrict__ ws) {
  int h = blockIdx.x, t = threadIdx.x;
  const float* W = (h == 0) ? W1 : (h == 1) ? W2 : (h == 2) ? W3 : W4;
  const float* a = (h == 0) ? a1 : (h == 1) ? a2 : (h == 2) ? a3 : a4;
  __shared__ float aL[F];
  __shared__ float part[F][33];   // +1 pad: conflict-free row sums

  if (t < F) aL[t] = a[t];
  __syncthreads();

  int c = t & 31, r8 = t >> 5;    // chunk, row-octet
#pragma unroll
  for (int it = 0; it < 16; ++it) {
    int row = it * 8 + r8;
    float4 w = ((const float4*)(W + row * F))[c];
    part[row][c] = w.x * aL[4 * c] + w.y * aL[4 * c + 1] +
                   w.z * aL[4 * c + 2] + w.w * aL[4 * c + 3];
  }
  __syncthreads();

  if (t < F) {
    float s = 0.f;
#pragma unroll
    for (int c2 = 0; c2 < 32; ++c2) s += part[t][c2];
    ws[OFF_WEFF + h * F + t] = s;
  }
}

// ---------------------------------------------------------------------------
// K2 (lane-per-chunk rewrite): lane c in each 32-lane half owns float4
// chunk c of one node => each global load instruction reads 2 whole nodes,
// 1 KB fully contiguous (perfect coalescing). Score = 32-lane reduction of
// in-register dot4 (rowsum16 DPP + 1 ds_swizzle); pool accumulates
// e_h * f4 into registers. Features NEVER touch LDS (R0-R3's wall: fixed
// ~12 us/CU of DS-pipe work regardless of occupancy); VGPR footprint
// ~70-80 (R4's wall: ~100+ VGPRs -> 2 blocks/CU, latency-bound). All 4
// feature loads issued up-front, consumed in order.
// R1 lesson kept: NO __threadfence fusion (agent-scope L2 writeback).
// ---------------------------------------------------------------------------
__global__ __launch_bounds__(256, 4) void k_main(
    const float* __restrict__ feat, float* __restrict__ ws) {
  int g = blockIdx.x >> 6;
  int slice = blockIdx.x & (NSLICE - 1);
  int t = threadIdx.x;
  int c  = t & 31;          // chunk within node
  int q  = (t >> 5) & 1;    // which node of the wave's pair
  int wv = t >> 6;          // wave 0..3

  // w_eff chunk for my lane, 4 heads (L2-resident, 16 VGPRs)
  const float4* wp = (const float4*)(ws + OFF_WEFF);
  float4 w4[4];
#pragma unroll
  for (int h = 0; h < 4; ++h) w4[h] = wp[h * 32 + c];

  const float4* fb =
      (const float4*)(feat + ((size_t)g * NN + slice * SNODES) * F);

  // Issue all 4 node-loads up-front (64 B/thread in flight).
  float4 ld[4];
#pragma unroll
  for (int p = 0; p < 4; ++p) {
    int n = p * 8 + wv * 2 + q;
    ld[p] = fb[n * 32 + c];
  }

  float4 acc[4];
#pragma unroll
  for (int h = 0; h < 4; ++h) acc[h] = make_float4(0.f, 0.f, 0.f, 0.f);
  float4 se = make_float4(0.f, 0.f, 0.f, 0.f);  // exp-sums over my 4 nodes

#pragma unroll
  for (int p = 0; p < 4; ++p) {
    float4 f = ld[p];
    float s0 = sum32(dot4(f, w4[0]));
    float s1 = sum32(dot4(f, w4[1]));
    float s2 = sum32(dot4(f, w4[2]));
    float s3 = sum32(dot4(f, w4[3]));
    // No max-subtraction: Xavier-bounded scores keep exp() in fp32 range.
    float e0 = __expf(s0), e1 = __expf(s1), e2 = __expf(s2), e3 = __expf(s3);
    se.x += e0; se.y += e1; se.z += e2; se.w += e3;
    acc[0].x += e0 * f.x; acc[0].y += e0 * f.y; acc[0].z += e0 * f.z; acc[0].w += e0 * f.w;
    acc[1].x += e1 * f.x; acc[1].y += e1 * f.y; acc[1].z += e1 * f.z; acc[1].w += e1 * f.w;
    acc[2].x += e2 * f.x; acc[2].y += e2 * f.y; acc[2].z += e2 * f.z; acc[2].w += e2 * f.w;
    acc[3].x += e3 * f.x; acc[3].y += e3 * f.y; acc[3].z += e3 * f.z; acc[3].w += e3 * f.w;
  }

  // ---- Final combine across the 8 (wave, half) groups via LDS (once) ----
  __shared__ float4 red[4][8][33];   // [head][grp][chunk], stride-1 c reads
  __shared__ float4 seR[8];
  int grp = wv * 2 + q;
#pragma unroll
  for (int h = 0; h < 4; ++h) red[h][grp][c] = acc[h];
  if (c == 0) seR[grp] = se;   // identical across the 32 lanes of the half
  __syncthreads();

  if (t < 128) {
    int h = t >> 5, cc = t & 31;
    float4 s = make_float4(0.f, 0.f, 0.f, 0.f);
#pragma unroll
    for (int gg = 0; gg < 8; ++gg) {
      float4 v = red[h][gg][cc];
      s.x += v.x; s.y += v.y; s.z += v.z; s.w += v.w;
    }
    ((float4*)(ws + OFF_FP))[(size_t)(g * NSLICE + slice) * 128 + h * 32 + cc] = s;
  }
  if (t == 0) {
    float4 L = make_float4(0.f, 0.f, 0.f, 0.f);
#pragma unroll
    for (int gg = 0; gg < 8; ++gg) {
      float4 v = seR[gg];
      L.x += v.x; L.y += v.y; L.z += v.z; L.w += v.w;
    }
    ((float4*)(ws + OFF_LP))[g * NSLICE + slice] = L;
  }
}

// ---------------------------------------------------------------------------
// K3: combine slice partials, normalize, pooled@W_h, concat@Wo, ELU.
// One block (256 threads) per group; coalesced float4 rows + LDS combine.
// ---------------------------------------------------------------------------
__global__ __launch_bounds__(256) void k_final(
    const float* __restrict__ W1, const float* __restrict__ W2,
    const float* __restrict__ W3, const float* __restrict__ W4,
    const float* __restrict__ Wo, const float* __restrict__ ws,
    float* __restrict__ out) {
  int g = blockIdx.x;
  int t = threadIdx.x;  // 0..255

  // Scratch layout (float4 indices):
  //   f4[0..255]   : pooled half-sums (2 x 128)  -> later Wo GEMV partials
  //   f4[256..383] : normalized fp (4 heads x 128 floats)
  //   f4[512..767] : W-GEMV partials (8 x 32)
  //   f4[768..895] : multi (512 floats)
  __shared__ float4 f4[896];
  __shared__ float invl[4];
  float* fbuf = (float*)f4;

  const float4* FP4 = (const float4*)(ws + OFF_FP) + (size_t)g * NSLICE * 128;

  if (t < 4) {
    float s = 0.f;
#pragma unroll
    for (int sl = 0; sl < NSLICE; ++sl)
      s += ws[OFF_LP + (g * NSLICE + sl) * 4 + t];
    invl[t] = 1.0f / s;
  }
  // Pooled half-sums: thread (j, half) sums 32 slices of element j.
  {
    int j = t & 127, half = t >> 7;
    float4 s4 = make_float4(0.f, 0.f, 0.f, 0.f);
#pragma unroll
    for (int sl = 0; sl < 32; ++sl) {
      float4 v = FP4[(size_t)(half * 32 + sl) * 128 + j];
      s4.x += v.x; s4.y += v.y; s4.z += v.z; s4.w += v.w;
    }
    f4[half * 128 + j] = s4;
  }
  __syncthreads();
  if (t < 128) {
    float4 a = f4[t], b = f4[128 + t];
    float inv = invl[t >> 5];
    f4[256 + t] = make_float4((a.x + b.x) * inv, (a.y + b.y) * inv,
                              (a.z + b.z) * inv, (a.w + b.w) * inv);
  }
  __syncthreads();

  // multi[h*128+col] = fp_h . W_h[:,col] — coalesced float4 rows of W_h,
  // 2 row-groups of 64 per head, LDS partial combine.
  {
    int c = t & 31, rg = (t >> 5) & 1, h = t >> 6;
    const float* Wsel = (h == 0) ? W1 : (h == 1) ? W2 : (h == 2) ? W3 : W4;
    const float4* W4p = (const float4*)Wsel;
    const float* fph = fbuf + 1024 + h * F;  // = f4[256 + h*32 ...]
    float4 acc = make_float4(0.f, 0.f, 0.f, 0.f);
#pragma unroll 8
    for (int k = 0; k < 64; ++k) {
      int i = rg * 64 + k;
      float s = fph[i];
      float4 w = W4p[i * 32 + c];
      acc.x += s * w.x; acc.y += s * w.y; acc.z += s * w.z; acc.w += s * w.w;
    }
    f4[512 + (h * 2 + rg) * 32 + c] = acc;
  }
  __syncthreads();
  if (t < 128) {
    int h = t >> 5, c = t & 31;
    float4 a = f4[512 + (h * 2) * 32 + c];
    float4 b = f4[512 + (h * 2 + 1) * 32 + c];
    f4[768 + h * 32 + c] = make_float4(a.x + b.x, a.y + b.y,
                                       a.z + b.z, a.w + b.w);
  }
  __syncthreads();

  // out[o] = elu(multi . Wo[:,o]) — coalesced float4 rows of Wo,
  // 16 row-groups of 32, LDS partial combine (reuses f4[0..255]).
  {
    int o4 = t & 15, rg = t >> 4;
    const float4* Wo4 = (const float4*)Wo;
    const float* mu = fbuf + 3072;  // = f4[768..]
    float4 acc = make_float4(0.f, 0.f, 0.f, 0.f);
#pragma unroll 8
    for (int k = 0; k < 32; ++k) {
      int i = rg * 32 + k;
      float s = mu[i];
      float4 w = Wo4[i * 16 + o4];
      acc.x += s * w.x; acc.y += s * w.y; acc.z += s * w.z; acc.w += s * w.w;
    }
    f4[rg * 16 + o4] = acc;
  }
  __syncthreads();
  if (t < OUTF) {
    float s = 0.f;
#pragma unroll
    for (int rg = 0; rg < 16; ++rg) s += fbuf[rg * 64 + t];
    out[g * OUTF + t] = (s > 0.f) ? s : expm1f(s);
  }
}

// ---------------------------------------------------------------------------
extern "C" void kernel_launch(void* const* d_in, const int* in_sizes, int n_in,
                              void* d_out, int out_size, void* d_ws, size_t ws_size,
                              hipStream_t stream) {
  const float* feat = (const float*)d_in[0];
  const float* W1 = (const float*)d_in[1];
  const float* a1 = (const float*)d_in[2];
  const float* W2 = (const float*)d_in[3];
  const float* a2 = (const float*)d_in[4];
  const float* W3 = (const float*)d_in[5];
  const float* a3 = (const float*)d_in[6];
  const float* W4 = (const float*)d_in[7];
  const float* a4 = (const float*)d_in[8];
  const float* Wo = (const float*)d_in[9];
  float* ws = (float*)d_ws;
  float* out = (float*)d_out;

  k_weff<<<4, 256, 0, stream>>>(W1, a1, W2, a2, W3, a3, W4, a4, ws);
  k_main<<<BG * NSLICE, 256, 0, stream>>>(feat, ws);
  k_final<<<BG, 256, 0, stream>>>(W1, W2, W3, W4, Wo, ws, out);
}